// Round 3
// baseline (303.865 us; speedup 1.0000x reference)
//
#include <hip/hip_runtime.h>

#define N_TOK 131072
#define DIM 64
#define K_CODES 1024
#define ALPHA 0.9f
#define ROWS 64                 // tokens per block
#define NBLK (N_TOK / ROWS)     // 2048 blocks
#define NCHUNK 8                // 8 chunks x 128 codes

typedef short bf16x8 __attribute__((ext_vector_type(8)));
typedef float f32x4  __attribute__((ext_vector_type(4)));

// float -> bf16 bits, round-to-nearest-even
__device__ __forceinline__ short f2bf(float f) {
    unsigned u = __builtin_bit_cast(unsigned, f);
    u += 0x7fffu + ((u >> 16) & 1u);
    return (short)(u >> 16);
}

// ---------------- prep: W -> bf16 (linear), w2p3[k] = 3 + ||w_k||^2 ----------------
__global__ __launch_bounds__(256) void prep_kernel(const float* __restrict__ W,
                                                   short* __restrict__ Wb,
                                                   float* __restrict__ w2p3) {
    int t = blockIdx.x * 256 + threadIdx.x;       // 0..2047 (8 blocks)
    // coalesced convert: 16384 float4 across 2048 threads
#pragma unroll
    for (int i = 0; i < 8; ++i) {
        int p = t + i * 2048;
        float4 v = ((const float4*)W)[p];
        short4 s = { f2bf(v.x), f2bf(v.y), f2bf(v.z), f2bf(v.w) };
        ((short4*)Wb)[p] = s;
    }
    // per-row ||w||^2 (first 1024 threads; rows are L2-hot)
    if (t < K_CODES) {
        const float4* wr = (const float4*)(W + (size_t)t * DIM);
        float s = 0.f;
#pragma unroll
        for (int i = 0; i < DIM / 4; ++i) {
            float4 v = wr[i];
            s += v.x * v.x + v.y * v.y + v.z * v.z + v.w * v.w;
        }
        w2p3[t] = 3.0f + s;
    }
}

// ---------------- main fused kernel: no LDS staging, no loop barriers ----------------
__global__ __launch_bounds__(256, 4) void vq_kernel(const float* __restrict__ x,
                                                    const float* __restrict__ W,
                                                    const short* __restrict__ Wb,
                                                    const float* __restrict__ w2p3,
                                                    float* __restrict__ out,
                                                    float* __restrict__ blocksum) {
    __shared__ unsigned red[4][ROWS];   // per-wave row minima (packed)
    __shared__ int   jrow[ROWS];
    __shared__ float wavesum[4];

    const int t    = threadIdx.x;
    const int wv   = t >> 6;            // wave 0..3: owns codes {c*128 + wv*32 .. +32}
    const int l15  = t & 15;
    const int lg   = (t & 63) >> 4;
    const int row0 = blockIdx.x * ROWS;

    // ---- A fragments (x rows, global -> regs, bf16) + x^2 partial ----
    // 16x16x32 A layout: row = lane&15, k = (lane>>4)*8 + e
    bf16x8 afrag[4][2];
    float x2part = 0.f;
#pragma unroll
    for (int rt = 0; rt < 4; ++rt)
#pragma unroll
        for (int ks = 0; ks < 2; ++ks) {
            const float* p = x + (size_t)(row0 + rt * 16 + l15) * DIM + ks * 32 + lg * 8;
            float4 a0 = *(const float4*)p;
            float4 a1 = *(const float4*)(p + 4);
            x2part += a0.x * a0.x + a0.y * a0.y + a0.z * a0.z + a0.w * a0.w +
                      a1.x * a1.x + a1.y * a1.y + a1.z * a1.z + a1.w * a1.w;
            bf16x8 f = { f2bf(a0.x), f2bf(a0.y), f2bf(a0.z), f2bf(a0.w),
                         f2bf(a1.x), f2bf(a1.y), f2bf(a1.z), f2bf(a1.w) };
            afrag[rt][ks] = f;
        }

    // running packed argmin: high 22 bits = score bits of (3 + w2 - 2*dot), low 10 = k
    unsigned best[4][4];
#pragma unroll
    for (int rt = 0; rt < 4; ++rt)
#pragma unroll
        for (int j = 0; j < 4; ++j) best[rt][j] = 0xFFFFFFFFu;

    // lane-fixed base: code row (wv*32 + l15), k-group lg
    const short* wl = Wb + ((wv * 32 + l15) * DIM + lg * 8);

#pragma unroll
    for (int c = 0; c < NCHUNK; ++c) {
#pragma unroll
        for (int ct = 0; ct < 2; ++ct) {
            const short* wp = wl + (c * 128 + ct * 16) * DIM;
            bf16x8 b0 = *(const bf16x8*)wp;          // k  0..31 (this lg slice)
            bf16x8 b1 = *(const bf16x8*)(wp + 32);   // k 32..63
            unsigned kidx = (unsigned)(c * 128 + wv * 32 + ct * 16 + l15);
            float w2v = w2p3[kidx];
#pragma unroll
            for (int rt = 0; rt < 4; ++rt) {
                f32x4 acc = {0.f, 0.f, 0.f, 0.f};
                acc = __builtin_amdgcn_mfma_f32_16x16x32_bf16(afrag[rt][0], b0, acc, 0, 0, 0);
                acc = __builtin_amdgcn_mfma_f32_16x16x32_bf16(afrag[rt][1], b1, acc, 0, 0, 0);
                // C layout: col = lane&15 (= this kidx), row = lg*4 + j
#pragma unroll
                for (int j = 0; j < 4; ++j) {
                    float s = fmaf(-2.f, acc[j], w2v);                       // in [2.81,3.19]
                    unsigned pk = (__builtin_bit_cast(unsigned, s) & 0xFFFFFC00u) | kidx;
                    best[rt][j] = min(best[rt][j], pk);
                }
            }
        }
    }

    // ---- cross-lane reduce: butterfly over the 16 l15 lanes ----
#pragma unroll
    for (int rt = 0; rt < 4; ++rt)
#pragma unroll
        for (int j = 0; j < 4; ++j) {
            unsigned v = best[rt][j];
            v = min(v, (unsigned)__shfl_xor((int)v, 1));
            v = min(v, (unsigned)__shfl_xor((int)v, 2));
            v = min(v, (unsigned)__shfl_xor((int)v, 4));
            v = min(v, (unsigned)__shfl_xor((int)v, 8));
            if (l15 == 0) red[wv][rt * 16 + lg * 4 + j] = v;   // row-min over this wave's codes
        }
    __syncthreads();

    float psum = 0.25f * x2part;        // each of 4 waves loaded the same x tile
    if (t < ROWS) {
        unsigned m = min(min(red[0][t], red[1][t]), min(red[2][t], red[3][t]));
        jrow[t] = (int)(m & 1023u);
        psum += __builtin_bit_cast(float, m & 0xFFFFFC00u) - 3.0f;   // w2 - 2*dot (quantized)
    }
    __syncthreads();

    // ---- gather W[j] (fp32, L2) -> out. 4 threads per row, 64B each ----
    {
        int r  = t >> 2;
        int cc = t & 3;
        int j  = jrow[r];
        const float4* wr = (const float4*)(W + (size_t)j * DIM + cc * 16);
        float4* od = (float4*)(out + (size_t)(row0 + r) * DIM + cc * 16);
#pragma unroll
        for (int i = 0; i < 4; ++i) od[i] = wr[i];
    }

    // ---- block reduce loss partial ----
#pragma unroll
    for (int off = 32; off; off >>= 1) psum += __shfl_down(psum, off);
    if ((t & 63) == 0) wavesum[t >> 6] = psum;
    __syncthreads();
    if (t == 0) blocksum[blockIdx.x] = wavesum[0] + wavesum[1] + wavesum[2] + wavesum[3];
}

// ---------------- deterministic finish ----------------
__global__ __launch_bounds__(256) void finish_kernel(const float* __restrict__ bs,
                                                     float* __restrict__ out) {
    __shared__ float wavesum[4];
    int t = threadIdx.x;
    float s = 0.f;
    for (int i = t; i < NBLK; i += 256) s += bs[i];
#pragma unroll
    for (int off = 32; off; off >>= 1) s += __shfl_down(s, off);
    if ((t & 63) == 0) wavesum[t >> 6] = s;
    __syncthreads();
    if (t == 0)
        out[(size_t)N_TOK * DIM] = (wavesum[0] + wavesum[1] + wavesum[2] + wavesum[3]) *
                                   ((1.0f + ALPHA) / (float)N_TOK);
}

extern "C" void kernel_launch(void* const* d_in, const int* in_sizes, int n_in,
                              void* d_out, int out_size, void* d_ws, size_t ws_size,
                              hipStream_t stream) {
    const float* x = (const float*)d_in[0];
    const float* W = (const float*)d_in[1];
    float* out = (float*)d_out;
    float* ws  = (float*)d_ws;

    float* blocksum = ws;                   // 2048 floats
    float* w2p3     = ws + 2048;            // 1024 floats
    short* Wb       = (short*)(ws + 3072);  // 65536 bf16 = 128 KB

    prep_kernel<<<8, 256, 0, stream>>>(W, Wb, w2p3);
    vq_kernel<<<NBLK, 256, 0, stream>>>(x, W, Wb, w2p3, out, blocksum);
    finish_kernel<<<1, 256, 0, stream>>>(blocksum, out);
}

// Round 4
// 108.220 us; speedup vs baseline: 2.8079x; 2.8079x over previous
//
#include <hip/hip_runtime.h>

#define N_TOK 131072
#define DIM 64
#define K_CODES 1024
#define ALPHA 0.9f
#define ROWS 64                   // tokens per block
#define NBLK (N_TOK / ROWS)       // 2048 blocks
#define NCHUNK 8                  // 8 chunks x 128 codes
#define CHUNK_BYTES 16384         // 128 codes * 64 elem * 2B bf16

typedef short bf16x8 __attribute__((ext_vector_type(8)));
typedef float f32x4  __attribute__((ext_vector_type(4)));

__device__ __forceinline__ short f2bf(float f) {
    unsigned u = __builtin_bit_cast(unsigned, f);
    u += 0x7fffu + ((u >> 16) & 1u);
    return (short)(u >> 16);
}
__device__ __forceinline__ unsigned umin2(unsigned a, unsigned b) { return a < b ? a : b; }

// ---------------- prep: Wb = bf16 PRE-SWIZZLED (16B group g' holds source group g'^(r&7)),
// ---------------- w2p3[k] = 3 + ||w_k||^2
__global__ __launch_bounds__(256) void prep_kernel(const float* __restrict__ W,
                                                   short* __restrict__ Wb,
                                                   float* __restrict__ w2p3) {
    int u = blockIdx.x * 256 + threadIdx.x;      // 0..8191 : one 16B bf16 group each
    int r = u >> 3;                              // code row 0..1023
    int gp = u & 7;                              // dest group
    int g  = gp ^ (r & 7);                       // source group (XOR swizzle)
    const float4* s = (const float4*)(W + (size_t)r * DIM + g * 8);
    float4 a = s[0], b = s[1];
    bf16x8 v = { f2bf(a.x), f2bf(a.y), f2bf(a.z), f2bf(a.w),
                 f2bf(b.x), f2bf(b.y), f2bf(b.z), f2bf(b.w) };
    *(bf16x8*)(Wb + (size_t)u * 8) = v;

    if (u < K_CODES) {
        const float4* wr = (const float4*)(W + (size_t)u * DIM);
        float sacc = 0.f;
#pragma unroll
        for (int i = 0; i < DIM / 4; ++i) {
            float4 t = wr[i];
            sacc += t.x * t.x + t.y * t.y + t.z * t.z + t.w * t.w;
        }
        w2p3[u] = 3.0f + sacc;
    }
}

// ---------------- main fused kernel ----------------
__global__ __launch_bounds__(256, 2) void vq_kernel(const float* __restrict__ x,
                                                    const float* __restrict__ W,
                                                    const short* __restrict__ Wb,
                                                    const float* __restrict__ w2p3,
                                                    float* __restrict__ out,
                                                    float* __restrict__ blocksum) {
    __shared__ __align__(16) unsigned char wbuf[2 * CHUNK_BYTES];  // 32 KB dbuf
    __shared__ unsigned red[4][ROWS];
    __shared__ int   jrow[ROWS];
    __shared__ float wavesum[4];

    const int t    = threadIdx.x;
    const int wv   = t >> 6;          // wave 0..3 : owns codes {c*128 + wv*32 .. +32}
    const int lane = t & 63;
    const int l15  = t & 15;
    const int lg   = lane >> 4;
    const int row0 = blockIdx.x * ROWS;

    // ---- A fragments (all 64 rows, every wave) + x^2 partial ----
    bf16x8 afrag[4][2];
    float x2part = 0.f;
#pragma unroll
    for (int rt = 0; rt < 4; ++rt)
#pragma unroll
        for (int ks = 0; ks < 2; ++ks) {
            const float* p = x + (size_t)(row0 + rt * 16 + l15) * DIM + ks * 32 + lg * 8;
            float4 a0 = *(const float4*)p;
            float4 a1 = *(const float4*)(p + 4);
            x2part += a0.x * a0.x + a0.y * a0.y + a0.z * a0.z + a0.w * a0.w +
                      a1.x * a1.x + a1.y * a1.y + a1.z * a1.z + a1.w * a1.w;
            bf16x8 f = { f2bf(a0.x), f2bf(a0.y), f2bf(a0.z), f2bf(a0.w),
                         f2bf(a1.x), f2bf(a1.y), f2bf(a1.z), f2bf(a1.w) };
            afrag[rt][ks] = f;
        }

    // ---- preload this lane's w2p3 values (16 regs, no loads in hot loop) ----
    float w2v[NCHUNK][2];
#pragma unroll
    for (int c = 0; c < NCHUNK; ++c)
#pragma unroll
        for (int ct = 0; ct < 2; ++ct)
            w2v[c][ct] = w2p3[c * 128 + wv * 32 + ct * 16 + l15];

    // ---- stage chunk 0 (wave-partitioned global_load_lds, 16B/lane) ----
#pragma unroll
    for (int i = 0; i < 4; ++i) {
        int off = wv * 4096 + i * 1024;
        __builtin_amdgcn_global_load_lds(
            (const __attribute__((address_space(1))) unsigned*)((const unsigned char*)Wb + off + lane * 16),
            (__attribute__((address_space(3))) unsigned*)(wbuf + off),
            16, 0, 0);
    }

    unsigned best[4][4];
#pragma unroll
    for (int rt = 0; rt < 4; ++rt)
#pragma unroll
        for (int j = 0; j < 4; ++j) best[rt][j] = 0xFFFFFFFFu;

    __syncthreads();   // drains vmcnt -> chunk 0 ready

#pragma unroll
    for (int c = 0; c < NCHUNK; ++c) {
        // issue next-chunk DMA first (hides under compute; buf^1 free since barrier c-1)
        if (c + 1 < NCHUNK) {
#pragma unroll
            for (int i = 0; i < 4; ++i) {
                int off = wv * 4096 + i * 1024;
                __builtin_amdgcn_global_load_lds(
                    (const __attribute__((address_space(1))) unsigned*)
                        ((const unsigned char*)Wb + (size_t)(c + 1) * CHUNK_BYTES + off + lane * 16),
                    (__attribute__((address_space(3))) unsigned*)(wbuf + ((c + 1) & 1) * CHUNK_BYTES + off),
                    16, 0, 0);
            }
        }

        const unsigned char* wb = wbuf + (c & 1) * CHUNK_BYTES;
#pragma unroll
        for (int ct = 0; ct < 2; ++ct) {
            int r  = wv * 32 + ct * 16 + l15;        // code row within chunk
            int sw = (r & 7) << 4;
            bf16x8 b0 = *(const bf16x8*)(wb + r * 128 + ((lg * 16) ^ sw));
            bf16x8 b1 = *(const bf16x8*)(wb + r * 128 + ((64 + lg * 16) ^ sw));
            unsigned kidx = (unsigned)(c * 128 + r);
            float w2c = w2v[c][ct];
#pragma unroll
            for (int rt = 0; rt < 4; ++rt) {
                f32x4 acc = {0.f, 0.f, 0.f, 0.f};
                acc = __builtin_amdgcn_mfma_f32_16x16x32_bf16(afrag[rt][0], b0, acc, 0, 0, 0);
                acc = __builtin_amdgcn_mfma_f32_16x16x32_bf16(afrag[rt][1], b1, acc, 0, 0, 0);
                // C layout: col = lane&15 (= kidx), row = lg*4 + j  -> x row rt*16+lg*4+j
#pragma unroll
                for (int j = 0; j < 4; ++j) {
                    float s = fmaf(-2.f, acc[j], w2c);                      // 3+w2-2dot in [2,4)
                    unsigned pk = (__builtin_bit_cast(unsigned, s) & 0xFFFFFC00u) | kidx;
                    best[rt][j] = umin2(best[rt][j], pk);
                }
            }
        }
        __syncthreads();   // all reads of buf done + next-chunk DMA drained
    }

    // ---- cross-lane argmin: butterfly over the 16 l15 lanes ----
#pragma unroll
    for (int rt = 0; rt < 4; ++rt)
#pragma unroll
        for (int j = 0; j < 4; ++j) {
            unsigned v = best[rt][j];
            v = umin2(v, (unsigned)__shfl_xor((int)v, 1));
            v = umin2(v, (unsigned)__shfl_xor((int)v, 2));
            v = umin2(v, (unsigned)__shfl_xor((int)v, 4));
            v = umin2(v, (unsigned)__shfl_xor((int)v, 8));
            if (l15 == 0) red[wv][rt * 16 + lg * 4 + j] = v;
        }
    __syncthreads();

    float psum = 0.25f * x2part;     // 4 waves duplicated the same x tile
    if (t < ROWS) {
        unsigned m = umin2(umin2(red[0][t], red[1][t]), umin2(red[2][t], red[3][t]));
        jrow[t] = (int)(m & 1023u);
        psum += __builtin_bit_cast(float, m & 0xFFFFFC00u) - 3.0f;   // w2 - 2dot (quantized)
    }
    __syncthreads();

    // ---- gather W[j] fp32 (L2-hot) -> out ----
    {
        int r  = t >> 2;
        int cc = t & 3;
        int j  = jrow[r];
        const float4* wr = (const float4*)(W + (size_t)j * DIM + cc * 16);
        float4* od = (float4*)(out + (size_t)(row0 + r) * DIM + cc * 16);
#pragma unroll
        for (int i = 0; i < 4; ++i) od[i] = wr[i];
    }

    // ---- block-reduce loss partial ----
#pragma unroll
    for (int off = 32; off; off >>= 1) psum += __shfl_down(psum, off);
    if ((t & 63) == 0) wavesum[t >> 6] = psum;
    __syncthreads();
    if (t == 0) blocksum[blockIdx.x] = wavesum[0] + wavesum[1] + wavesum[2] + wavesum[3];
}

// ---------------- deterministic finish ----------------
__global__ __launch_bounds__(256) void finish_kernel(const float* __restrict__ bs,
                                                     float* __restrict__ out) {
    __shared__ float wavesum[4];
    int t = threadIdx.x;
    float s = 0.f;
    for (int i = t; i < NBLK; i += 256) s += bs[i];
#pragma unroll
    for (int off = 32; off; off >>= 1) s += __shfl_down(s, off);
    if ((t & 63) == 0) wavesum[t >> 6] = s;
    __syncthreads();
    if (t == 0)
        out[(size_t)N_TOK * DIM] = (wavesum[0] + wavesum[1] + wavesum[2] + wavesum[3]) *
                                   ((1.0f + ALPHA) / (float)N_TOK);
}

extern "C" void kernel_launch(void* const* d_in, const int* in_sizes, int n_in,
                              void* d_out, int out_size, void* d_ws, size_t ws_size,
                              hipStream_t stream) {
    const float* x = (const float*)d_in[0];
    const float* W = (const float*)d_in[1];
    float* out = (float*)d_out;
    float* ws  = (float*)d_ws;

    float* blocksum = ws;                   // 2048 floats
    float* w2p3     = ws + 2048;            // 1024 floats
    short* Wb       = (short*)(ws + 3072);  // 65536 bf16 = 128 KB (pre-swizzled)

    prep_kernel<<<32, 256, 0, stream>>>(W, Wb, w2p3);
    vq_kernel<<<NBLK, 256, 0, stream>>>(x, W, Wb, w2p3, out, blocksum);
    finish_kernel<<<1, 256, 0, stream>>>(blocksum, out);
}

// Round 5
// 55.081 us; speedup vs baseline: 5.5167x; 1.9647x over previous
//
#include <hip/hip_runtime.h>

#define N_TOK 131072
#define DIM 64
#define K_CODES 1024
#define ALPHA 0.9f
#define ROWS 64                   // tokens per block
#define NBLK (N_TOK / ROWS)       // 2048 blocks
#define NCHUNK 8                  // 8 chunks x 128 codes
#define CHUNK_BYTES 16384         // 128 codes * 64 elem * 2B bf16

typedef short bf16x8 __attribute__((ext_vector_type(8)));
typedef float f32x4  __attribute__((ext_vector_type(4)));

__device__ __forceinline__ short f2bf(float f) {
    unsigned u = __builtin_bit_cast(unsigned, f);
    u += 0x7fffu + ((u >> 16) & 1u);
    return (short)(u >> 16);
}
__device__ __forceinline__ unsigned umin2(unsigned a, unsigned b) { return a < b ? a : b; }

// ---------------- prep: Wb = bf16 PRE-SWIZZLED (dest 16B-group gp holds source group gp^(r&7)),
// ---------------- w2p3[k] = 3 + ||w_k||^2
__global__ __launch_bounds__(256) void prep_kernel(const float* __restrict__ W,
                                                   short* __restrict__ Wb,
                                                   float* __restrict__ w2p3) {
    int u = blockIdx.x * 256 + threadIdx.x;      // 0..8191 : one 16B bf16 group each
    int r  = u >> 3;                             // code row 0..1023
    int gp = u & 7;                              // dest group
    int g  = gp ^ (r & 7);                       // source group (XOR swizzle)
    const float4* s = (const float4*)(W + (size_t)r * DIM + g * 8);
    float4 a = s[0], b = s[1];
    bf16x8 v = { f2bf(a.x), f2bf(a.y), f2bf(a.z), f2bf(a.w),
                 f2bf(b.x), f2bf(b.y), f2bf(b.z), f2bf(b.w) };
    *(bf16x8*)(Wb + (size_t)u * 8) = v;

    if (u < K_CODES) {
        const float4* wr = (const float4*)(W + (size_t)u * DIM);
        float sacc = 0.f;
#pragma unroll
        for (int i = 0; i < DIM / 4; ++i) {
            float4 t = wr[i];
            sacc += t.x * t.x + t.y * t.y + t.z * t.z + t.w * t.w;
        }
        w2p3[u] = 3.0f + sacc;
    }
}

// ---------------- main fused kernel ----------------
__global__ __launch_bounds__(256, 2) void vq_kernel(const float* __restrict__ x,
                                                    const float* __restrict__ W,
                                                    const short* __restrict__ Wb,
                                                    const float* __restrict__ w2p3,
                                                    float* __restrict__ out,
                                                    float* __restrict__ blocksum) {
    __shared__ __align__(16) unsigned char wbuf[2 * CHUNK_BYTES];  // 32 KB dbuf
    __shared__ float    w2s[K_CODES];                              // 4 KB
    __shared__ unsigned red[4][32];
    __shared__ int      jrow[ROWS];
    __shared__ float    wavesum[4];

    const int t        = threadIdx.x;
    const int wv       = t >> 6;
    const int lane     = t & 63;
    const int l15      = t & 15;
    const int lg       = lane >> 4;
    const int rowhalf  = wv >> 1;     // wave handles rows  [32*rowhalf, +32)
    const int codehalf = wv & 1;      // wave handles codes [64*codehalf, +64) of each chunk
    const int row0     = blockIdx.x * ROWS;

    // ---- stage w2p3 into LDS (4 KB, coalesced) ----
#pragma unroll
    for (int i = 0; i < K_CODES / 256; ++i) w2s[t + i * 256] = w2p3[t + i * 256];

    // ---- A fragments (this wave's 32 rows) + x^2 partial ----
    bf16x8 afrag[2][2];
    float x2part = 0.f;
#pragma unroll
    for (int rt = 0; rt < 2; ++rt)
#pragma unroll
        for (int ks = 0; ks < 2; ++ks) {
            const float* p = x + (size_t)(row0 + rowhalf * 32 + rt * 16 + l15) * DIM + ks * 32 + lg * 8;
            float4 a0 = *(const float4*)p;
            float4 a1 = *(const float4*)(p + 4);
            x2part += a0.x * a0.x + a0.y * a0.y + a0.z * a0.z + a0.w * a0.w +
                      a1.x * a1.x + a1.y * a1.y + a1.z * a1.z + a1.w * a1.w;
            bf16x8 f = { f2bf(a0.x), f2bf(a0.y), f2bf(a0.z), f2bf(a0.w),
                         f2bf(a1.x), f2bf(a1.y), f2bf(a1.z), f2bf(a1.w) };
            afrag[rt][ks] = f;
        }

    // ---- stage chunk 0 (wave-partitioned global_load_lds, 16B/lane) ----
#pragma unroll
    for (int i = 0; i < 4; ++i) {
        int off = wv * 4096 + i * 1024;
        __builtin_amdgcn_global_load_lds(
            (const __attribute__((address_space(1))) unsigned*)((const unsigned char*)Wb + off + lane * 16),
            (__attribute__((address_space(3))) unsigned*)(wbuf + off),
            16, 0, 0);
    }

    unsigned best[2][4];
#pragma unroll
    for (int rt = 0; rt < 2; ++rt)
#pragma unroll
        for (int j = 0; j < 4; ++j) best[rt][j] = 0xFFFFFFFFu;

    __syncthreads();   // chunk 0 ready (barrier drains vmcnt)

    for (int c = 0; c < NCHUNK; ++c) {          // NOT unrolled: keeps pressure low
        if (c + 1 < NCHUNK) {                   // issue next-chunk DMA, lands during compute
#pragma unroll
            for (int i = 0; i < 4; ++i) {
                int off = wv * 4096 + i * 1024;
                __builtin_amdgcn_global_load_lds(
                    (const __attribute__((address_space(1))) unsigned*)
                        ((const unsigned char*)Wb + (size_t)(c + 1) * CHUNK_BYTES + off + lane * 16),
                    (__attribute__((address_space(3))) unsigned*)(wbuf + ((c + 1) & 1) * CHUNK_BYTES + off),
                    16, 0, 0);
            }
        }

        const unsigned char* wb = wbuf + (c & 1) * CHUNK_BYTES;
#pragma unroll
        for (int ct = 0; ct < 4; ++ct) {
            int r  = codehalf * 64 + ct * 16 + l15;     // code row within chunk
            int sw = (r & 7) << 4;
            bf16x8 b0 = *(const bf16x8*)(wb + r * 128 + ((lg * 16) ^ sw));
            bf16x8 b1 = *(const bf16x8*)(wb + r * 128 + ((64 + lg * 16) ^ sw));
            unsigned kidx = (unsigned)(c * 128 + r);
            float w2c = w2s[kidx];                       // broadcast ds_read
#pragma unroll
            for (int rt = 0; rt < 2; ++rt) {
                f32x4 acc = {0.f, 0.f, 0.f, 0.f};
                acc = __builtin_amdgcn_mfma_f32_16x16x32_bf16(afrag[rt][0], b0, acc, 0, 0, 0);
                acc = __builtin_amdgcn_mfma_f32_16x16x32_bf16(afrag[rt][1], b1, acc, 0, 0, 0);
                // C layout: col = lane&15 (= kidx), row-in-tile = lg*4 + j
#pragma unroll
                for (int j = 0; j < 4; ++j) {
                    float s = fmaf(-2.f, acc[j], w2c);   // 3 + w2 - 2dot  in [2,4)
                    unsigned pk = (__builtin_bit_cast(unsigned, s) & 0xFFFFFC00u) | kidx;
                    best[rt][j] = umin2(best[rt][j], pk);
                }
            }
        }
        __syncthreads();   // buf reads done + next-chunk DMA drained
    }

    // ---- cross-lane argmin: butterfly over the 16 l15 lanes (code dim) ----
#pragma unroll
    for (int rt = 0; rt < 2; ++rt)
#pragma unroll
        for (int j = 0; j < 4; ++j) {
            unsigned v = best[rt][j];
            v = umin2(v, (unsigned)__shfl_xor((int)v, 1));
            v = umin2(v, (unsigned)__shfl_xor((int)v, 2));
            v = umin2(v, (unsigned)__shfl_xor((int)v, 4));
            v = umin2(v, (unsigned)__shfl_xor((int)v, 8));
            if (l15 == 0) red[wv][rt * 16 + lg * 4 + j] = v;
        }
    __syncthreads();

    float psum = 0.5f * x2part;      // two waves duplicated each x half-tile
    if (t < ROWS) {
        int rh = t >> 5, rr = t & 31;
        unsigned m = umin2(red[rh * 2][rr], red[rh * 2 + 1][rr]);
        jrow[t] = (int)(m & 1023u);
        psum += __builtin_bit_cast(float, m & 0xFFFFFC00u) - 3.0f;   // w2 - 2dot (quantized)
    }
    __syncthreads();

    // ---- gather W[j] fp32 (L2-hot) -> out ----
    {
        int r  = t >> 2;
        int cc = t & 3;
        int j  = jrow[r];
        const float4* wr = (const float4*)(W + (size_t)j * DIM + cc * 16);
        float4* od = (float4*)(out + (size_t)(row0 + r) * DIM + cc * 16);
#pragma unroll
        for (int i = 0; i < 4; ++i) od[i] = wr[i];
    }

    // ---- block-reduce loss partial ----
#pragma unroll
    for (int off = 32; off; off >>= 1) psum += __shfl_down(psum, off);
    if ((t & 63) == 0) wavesum[t >> 6] = psum;
    __syncthreads();
    if (t == 0) blocksum[blockIdx.x] = wavesum[0] + wavesum[1] + wavesum[2] + wavesum[3];
}

// ---------------- deterministic finish ----------------
__global__ __launch_bounds__(256) void finish_kernel(const float* __restrict__ bs,
                                                     float* __restrict__ out) {
    __shared__ float wavesum[4];
    int t = threadIdx.x;
    float s = 0.f;
    for (int i = t; i < NBLK; i += 256) s += bs[i];
#pragma unroll
    for (int off = 32; off; off >>= 1) s += __shfl_down(s, off);
    if ((t & 63) == 0) wavesum[t >> 6] = s;
    __syncthreads();
    if (t == 0)
        out[(size_t)N_TOK * DIM] = (wavesum[0] + wavesum[1] + wavesum[2] + wavesum[3]) *
                                   ((1.0f + ALPHA) / (float)N_TOK);
}

extern "C" void kernel_launch(void* const* d_in, const int* in_sizes, int n_in,
                              void* d_out, int out_size, void* d_ws, size_t ws_size,
                              hipStream_t stream) {
    const float* x = (const float*)d_in[0];
    const float* W = (const float*)d_in[1];
    float* out = (float*)d_out;
    float* ws  = (float*)d_ws;

    float* blocksum = ws;                   // 2048 floats
    float* w2p3     = ws + 2048;            // 1024 floats
    short* Wb       = (short*)(ws + 3072);  // 65536 bf16 = 128 KB (pre-swizzled)

    prep_kernel<<<32, 256, 0, stream>>>(W, Wb, w2p3);
    vq_kernel<<<NBLK, 256, 0, stream>>>(x, W, Wb, w2p3, out, blocksum);
    finish_kernel<<<1, 256, 0, stream>>>(blocksum, out);
}